// Round 1
// baseline (5487.197 us; speedup 1.0000x reference)
//
#include <hip/hip_runtime.h>

// SurfaceTransolver fused implementation, round 1: all-fp32, correctness-first.
//
// Decomposition:
//   K0a: Wlog[q=h*64+s][k] = (sum_c W_x[k][h*32+c] * W_slice[c][s]) / temp[h]   (512x256)
//        blog[q] = (sum_c b_x[h*32+c]*W_slice[c][s] + b_slice[s]) / temp[h]
//   K0b: Wfxt[col][k] = W_fx[k][col]  (transpose for row-major dot)
//   K1 : per 16-token tile: stage x -> LDS; logits GEMM (512 cols); softmax*mask -> w (LDS);
//        fx GEMM (256 cols, regs); accumulate num[hc][s] += fx*w, norm[q] += w  (per-block partials)
//   K2 : reduce partials -> slice_tokens (num/(norm+1e-5)); SDPA per head (S=64, DH=32);
//        PT[j][q] = sum_c out_slice[q][c] * W_proj[h*32+c][j]   (fold W_proj)
//   K3 : per 16-token tile: recompute w (same as K1 first half);
//        out[n][j] = mask*(mask*sum_q w[n][q]*PT[j][q] + b_proj[j])
//
// w is recomputed in K3 rather than stored (saves 410 MB of ws + traffic; costs ~52 GF fp32,
// which becomes nearly free once the GEMMs move to MFMA in a later round).

#define HID 256
#define NH  8
#define DH  32
#define NS  64
#define NQ  512              // NH*NS
#define TB  16               // tokens per tile
#define PSTRIDE 16896        // 256*64 (num) + 512 (norm)

// ---- shared helper: stage x tile, logits GEMM, softmax*mask -> w in `mid` ----
__device__ __forceinline__ void compute_w_tile(
    const float* __restrict__ x, const float* __restrict__ mask, int n0,
    const float* __restrict__ Wlog, const float* __restrict__ blog,
    float (*xs)[HID], float (*mid)[NQ], float* msk)
{
  const int t = threadIdx.x;
  {
    const float4* src = (const float4*)(x + (size_t)n0 * HID);
    float4* dst = (float4*)&xs[0][0];
#pragma unroll
    for (int i = 0; i < (TB * HID / 4) / 256; ++i)
      dst[t + i * 256] = src[t + i * 256];
    if (t < TB) msk[t] = mask[n0 + t];
  }
  __syncthreads();
  // logits GEMM: thread owns cols q0=t and q1=t+256; x rows broadcast from LDS.
  {
    const float4* wrow0 = (const float4*)(Wlog + (size_t)t * HID);
    const float4* wrow1 = (const float4*)(Wlog + (size_t)(t + 256) * HID);
    float acc0[TB], acc1[TB];
    const float b0 = blog[t], b1 = blog[t + 256];
#pragma unroll
    for (int tok = 0; tok < TB; ++tok) { acc0[tok] = b0; acc1[tok] = b1; }
    float4 wv0 = wrow0[0], wv1 = wrow1[0];
    for (int k4 = 0; k4 < HID / 4; ++k4) {
      const int nk = (k4 + 1 < HID / 4) ? k4 + 1 : k4;
      const float4 wn0 = wrow0[nk], wn1 = wrow1[nk];
#pragma unroll
      for (int tok = 0; tok < TB; ++tok) {
        const float4 xv = ((const float4*)xs[tok])[k4];
        acc0[tok] = fmaf(xv.x, wv0.x, acc0[tok]);
        acc0[tok] = fmaf(xv.y, wv0.y, acc0[tok]);
        acc0[tok] = fmaf(xv.z, wv0.z, acc0[tok]);
        acc0[tok] = fmaf(xv.w, wv0.w, acc0[tok]);
        acc1[tok] = fmaf(xv.x, wv1.x, acc1[tok]);
        acc1[tok] = fmaf(xv.y, wv1.y, acc1[tok]);
        acc1[tok] = fmaf(xv.z, wv1.z, acc1[tok]);
        acc1[tok] = fmaf(xv.w, wv1.w, acc1[tok]);
      }
      wv0 = wn0; wv1 = wn1;
    }
#pragma unroll
    for (int tok = 0; tok < TB; ++tok) {
      mid[tok][t] = acc0[tok];
      mid[tok][t + 256] = acc1[tok];
    }
  }
  __syncthreads();
  // softmax over s (64) per (tok, head) row, then * mask; rows owned by threads 0..127
  if (t < TB * NH) {
    const int tok = t >> 3, h = t & 7;
    float* row = &mid[tok][h * NS];
    float m = -1e30f;
    for (int s = 0; s < NS; ++s) m = fmaxf(m, row[s]);
    float sum = 0.f;
    for (int s = 0; s < NS; ++s) { const float e = __expf(row[s] - m); row[s] = e; sum += e; }
    const float inv = msk[tok] / sum;
    for (int s = 0; s < NS; ++s) row[s] *= inv;
  }
  __syncthreads();
}

// ---- K0a ----
__global__ __launch_bounds__(256) void k_build_wlog(
    const float* __restrict__ Wx, const float* __restrict__ bx,
    const float* __restrict__ Wsl, const float* __restrict__ bsl,
    const float* __restrict__ temp,
    float* __restrict__ Wlog, float* __restrict__ blog)
{
  const int q = blockIdx.x, k = threadIdx.x;
  const int h = q >> 6, s = q & 63;
  const float it = 1.0f / temp[h];
  float acc = 0.f;
#pragma unroll
  for (int c = 0; c < DH; ++c)
    acc = fmaf(Wx[k * HID + h * DH + c], Wsl[c * NS + s], acc);
  Wlog[(size_t)q * HID + k] = acc * it;
  if (k == 0) {
    float b = bsl[s];
    for (int c = 0; c < DH; ++c) b = fmaf(bx[h * DH + c], Wsl[c * NS + s], b);
    blog[q] = b * it;
  }
}

// ---- K0b ----
__global__ __launch_bounds__(256) void k_transpose256(
    const float* __restrict__ src, float* __restrict__ dst)
{
  const int r = blockIdx.x, c = threadIdx.x;
  dst[c * HID + r] = src[r * HID + c];
}

// ---- K1 ----
__global__ __launch_bounds__(256, 3) void k_pass1(
    const float* __restrict__ x, const float* __restrict__ mask,
    const float* __restrict__ Wlog, const float* __restrict__ blog,
    const float* __restrict__ Wfxt, const float* __restrict__ bfx,
    float* __restrict__ partials, int ntiles, int nb1)
{
  __shared__ float xs[TB][HID];    // 16 KB
  __shared__ float mid[TB][NQ];    // 32 KB (logits -> w)
  __shared__ float msk[TB];
  const int t = threadIdx.x;
  float num_acc[NS];
#pragma unroll
  for (int s = 0; s < NS; ++s) num_acc[s] = 0.f;
  float norm0 = 0.f, norm1 = 0.f;
  const int h_own = t >> 5;        // thread owns fx col hc = t  (h = t/32, c = t%32)

  for (int tile = blockIdx.x; tile < ntiles; tile += nb1) {
    __syncthreads();               // protect xs/mid from previous iteration's readers
    compute_w_tile(x, mask, tile * TB, Wlog, blog, xs, mid, msk);

    // norm[q] accumulation: thread owns q = t and q = t+256
    for (int tok = 0; tok < TB; ++tok) {
      norm0 += mid[tok][t];
      norm1 += mid[tok][t + 256];
    }

    // fx GEMM, col hc = t (in registers), then num[hc][s] update
    float facc[TB];
    const float b = bfx[t];
#pragma unroll
    for (int tok = 0; tok < TB; ++tok) facc[tok] = b;
    const float4* wrow = (const float4*)(Wfxt + (size_t)t * HID);
    float4 wv = wrow[0];
    for (int k4 = 0; k4 < HID / 4; ++k4) {
      const float4 wn = wrow[(k4 + 1 < HID / 4) ? k4 + 1 : k4];
#pragma unroll
      for (int tok = 0; tok < TB; ++tok) {
        const float4 xv = ((const float4*)xs[tok])[k4];
        facc[tok] = fmaf(xv.x, wv.x, facc[tok]);
        facc[tok] = fmaf(xv.y, wv.y, facc[tok]);
        facc[tok] = fmaf(xv.z, wv.z, facc[tok]);
        facc[tok] = fmaf(xv.w, wv.w, facc[tok]);
      }
      wv = wn;
    }
#pragma unroll
    for (int s = 0; s < NS; ++s) {
      float tmp = 0.f;
#pragma unroll
      for (int tok = 0; tok < TB; ++tok)
        tmp = fmaf(facc[tok], mid[tok][h_own * NS + s], tmp);  // 2-addr broadcast read
      num_acc[s] += tmp;
    }
  }

  float* pb = partials + (size_t)blockIdx.x * PSTRIDE;
  for (int s = 0; s < NS; ++s) pb[t * NS + s] = num_acc[s];   // num layout [hc][s]
  pb[16384 + t] = norm0;                                      // norm layout [q]
  pb[16384 + 256 + t] = norm1;
}

// ---- K2: reductions ----
__global__ __launch_bounds__(256) void k_reduce_norm(
    const float* __restrict__ partials, float* __restrict__ normbuf, int nb)
{
  const int p = blockIdx.x * 256 + threadIdx.x;  // 0..511
  float s = 0.f;
  for (int b = 0; b < nb; ++b) s += partials[(size_t)b * PSTRIDE + 16384 + p];
  normbuf[p] = s;
}

__global__ __launch_bounds__(256) void k_reduce_num(
    const float* __restrict__ partials, const float* __restrict__ normbuf,
    float* __restrict__ st, int nb)
{
  const int pidx = blockIdx.x * 256 + threadIdx.x;  // 0..16383, = hc*64+s
  const int hc = pidx >> 6, s = pidx & 63;
  const int h = hc >> 5, c = hc & 31;
  float acc = 0.f;
  for (int b = 0; b < nb; ++b) acc += partials[(size_t)b * PSTRIDE + pidx];  // coalesced
  st[(h * NS + s) * DH + c] = acc / (normbuf[h * NS + s] + 1e-5f);
}

// ---- K2: SDPA over slices, one block per head ----
__global__ __launch_bounds__(64) void k_sdpa(
    const float* __restrict__ st, const float* __restrict__ Wqkv,
    float* __restrict__ osl)
{
  __shared__ float stt[NS][DH + 1];
  __shared__ float kt[NS][DH + 1];
  __shared__ float vt[NS][DH + 1];
  const int h = blockIdx.x, sr = threadIdx.x;
  for (int i = sr; i < NS * DH; i += 64) stt[i >> 5][i & 31] = st[(size_t)h * NS * DH + i];
  __syncthreads();
  float qr[DH];
#pragma unroll
  for (int c = 0; c < DH; ++c) {
    float aq = 0.f, ak = 0.f, av = 0.f;
#pragma unroll
    for (int i = 0; i < DH; ++i) {
      const float sv = stt[sr][i];
      aq = fmaf(sv, Wqkv[i * 96 + c], aq);
      ak = fmaf(sv, Wqkv[i * 96 + 32 + c], ak);
      av = fmaf(sv, Wqkv[i * 96 + 64 + c], av);
    }
    qr[c] = aq; kt[sr][c] = ak; vt[sr][c] = av;
  }
  __syncthreads();
  float sc[NS];
  float m = -1e30f;
  const float scale = 0.17677669529663687f;  // 1/sqrt(32)
#pragma unroll
  for (int tt = 0; tt < NS; ++tt) {
    float a = 0.f;
#pragma unroll
    for (int c = 0; c < DH; ++c) a = fmaf(qr[c], kt[tt][c], a);
    a *= scale;
    sc[tt] = a;
    m = fmaxf(m, a);
  }
  float sum = 0.f;
#pragma unroll
  for (int tt = 0; tt < NS; ++tt) { const float e = __expf(sc[tt] - m); sc[tt] = e; sum += e; }
  const float inv = 1.f / sum;
#pragma unroll
  for (int c = 0; c < DH; ++c) {
    float o = 0.f;
#pragma unroll
    for (int tt = 0; tt < NS; ++tt) o = fmaf(sc[tt], vt[tt][c], o);
    osl[(size_t)h * NS * DH + sr * DH + c] = o * inv;
  }
}

// ---- K2: fold W_proj through out_slice: PT[j][q] ----
__global__ __launch_bounds__(512) void k_build_pt(
    const float* __restrict__ osl, const float* __restrict__ Wproj,
    float* __restrict__ PT)
{
  const int j = blockIdx.x, q = threadIdx.x;
  const int h = q >> 6;
  float acc = 0.f;
#pragma unroll
  for (int c = 0; c < DH; ++c)
    acc = fmaf(osl[q * DH + c], Wproj[(h * DH + c) * HID + j], acc);
  PT[j * NQ + q] = acc;
}

// ---- K3 ----
__global__ __launch_bounds__(256, 3) void k_pass3(
    const float* __restrict__ x, const float* __restrict__ mask,
    const float* __restrict__ Wlog, const float* __restrict__ blog,
    const float* __restrict__ PT, const float* __restrict__ bproj,
    float* __restrict__ out, int ntiles, int ngrid)
{
  __shared__ float xs[TB][HID];
  __shared__ float mid[TB][NQ];
  __shared__ float msk[TB];
  const int t = threadIdx.x;
  const float bp = bproj[t];
  for (int tile = blockIdx.x; tile < ntiles; tile += ngrid) {
    __syncthreads();
    compute_w_tile(x, mask, tile * TB, Wlog, blog, xs, mid, msk);
    float acc[TB];
#pragma unroll
    for (int tok = 0; tok < TB; ++tok) acc[tok] = 0.f;
    const float4* pr = (const float4*)(PT + (size_t)t * NQ);
    float4 pv = pr[0];
    for (int q4 = 0; q4 < NQ / 4; ++q4) {
      const float4 pn = pr[(q4 + 1 < NQ / 4) ? q4 + 1 : q4];
#pragma unroll
      for (int tok = 0; tok < TB; ++tok) {
        const float4 wv = ((const float4*)mid[tok])[q4];
        acc[tok] = fmaf(wv.x, pv.x, acc[tok]);
        acc[tok] = fmaf(wv.y, pv.y, acc[tok]);
        acc[tok] = fmaf(wv.z, pv.z, acc[tok]);
        acc[tok] = fmaf(wv.w, pv.w, acc[tok]);
      }
      pv = pn;
    }
    const int n0 = tile * TB;
#pragma unroll
    for (int tok = 0; tok < TB; ++tok) {
      const float mk = msk[tok];
      out[(size_t)(n0 + tok) * HID + t] = mk * (mk * acc[tok] + bp);
    }
  }
}

extern "C" void kernel_launch(void* const* d_in, const int* in_sizes, int n_in,
                              void* d_out, int out_size, void* d_ws, size_t ws_size,
                              hipStream_t stream)
{
  const float* x     = (const float*)d_in[0];
  const float* mask  = (const float*)d_in[1];
  const float* Wfx   = (const float*)d_in[2];
  const float* bfx   = (const float*)d_in[3];
  const float* Wx    = (const float*)d_in[4];
  const float* bx    = (const float*)d_in[5];
  const float* Wsl   = (const float*)d_in[6];
  const float* bsl   = (const float*)d_in[7];
  const float* Wqkv  = (const float*)d_in[8];
  const float* Wproj = (const float*)d_in[9];
  const float* bproj = (const float*)d_in[10];
  const float* temp  = (const float*)d_in[11];
  float* out = (float*)d_out;

  const int N = in_sizes[0] / HID;      // 200000
  const int ntiles = N / TB;            // 12500 (exact)

  char* ws = (char*)d_ws;
  size_t off = 0;
  float* wlog    = (float*)(ws + off); off += (size_t)NQ * HID * 4;   // 512 KB
  float* blog    = (float*)(ws + off); off += NQ * 4;
  float* wfxt    = (float*)(ws + off); off += (size_t)HID * HID * 4;  // 256 KB
  float* normbuf = (float*)(ws + off); off += NQ * 4;
  float* stb     = (float*)(ws + off); off += NQ * DH * 4;            // 64 KB
  float* osl     = (float*)(ws + off); off += NQ * DH * 4;            // 64 KB
  float* pt      = (float*)(ws + off); off += (size_t)HID * NQ * 4;   // 512 KB
  int nb1 = 768;                                                      // 3 blocks/CU
  while (nb1 > 1 && off + (size_t)nb1 * PSTRIDE * 4 > ws_size) nb1 >>= 1;
  float* partials = (float*)(ws + off);

  k_build_wlog<<<dim3(NQ), dim3(HID), 0, stream>>>(Wx, bx, Wsl, bsl, temp, wlog, blog);
  k_transpose256<<<dim3(HID), dim3(HID), 0, stream>>>(Wfx, wfxt);
  k_pass1<<<dim3(nb1), dim3(256), 0, stream>>>(x, mask, wlog, blog, wfxt, bfx,
                                               partials, ntiles, nb1);
  k_reduce_norm<<<dim3(2), dim3(256), 0, stream>>>(partials, normbuf, nb1);
  k_reduce_num<<<dim3(64), dim3(256), 0, stream>>>(partials, normbuf, stb, nb1);
  k_sdpa<<<dim3(NH), dim3(64), 0, stream>>>(stb, Wqkv, osl);
  k_build_pt<<<dim3(HID), dim3(NQ), 0, stream>>>(osl, Wproj, pt);
  k_pass3<<<dim3(768), dim3(256), 0, stream>>>(x, mask, wlog, blog, pt, bproj,
                                               out, ntiles, 768);
}

// Round 2
// 1705.610 us; speedup vs baseline: 3.2171x; 3.2171x over previous
//
#include <hip/hip_runtime.h>

// SurfaceTransolver round 2: split-bf16 MFMA (fp32 emulation via hi/lo bf16 pairs).
//
//   K0a: Wlog[q][k] = (sum_c W_x[k][h*32+c]*W_slice[c][s])/temp[h] -> bf16 hi/lo; blog f32
//   K0b: Wfxt_hi[c][k] = bf16(W_fx[k][c])                 (fx path: 1-product, pooling-tolerant)
//   K0c: WprojT hi/lo[j][hc] = split(W_proj[hc][j])
//   P1 : per 32-token tile: x->LDS(hi); logits = MFMA(x_hi,Wlog_hi); wave-shfl softmax -> w
//        wT_hi LDS; fx = MFMA(x_hi,Wfxt_hi)+b -> fxT LDS; pool MFMA num[s][hc] += wT*fxT (persistent acc)
//   K2 : reduce partials -> st[q][c]; SDPA per head; oslT hi/lo[h][c][s]
//   P3 : per 32-token tile: x->LDS(hi,lo); logits 3-product; softmax -> w hi/lo LDS;
//        stage1: ox[tok][hc] = MFMA3(w, oslT) -> LDS (reuses x space);
//        stage2: out = mask*(mask*MFMA3(ox, WprojT) + b_proj)
//
// MFMA 16x16x32 bf16 layouts (learn_hip m89/m92-verified):
//   A: row=lane&15, k=(lane>>4)*8+j (8 contig bf16) ; B: col=lane&15, same k
//   C/D: col=lane&15, row=(lane>>4)*4+reg

#define HID 256
#define NH  8
#define DH  32
#define NS  64
#define NQ  512
#define MT  32                 // tokens per tile
#define PSTRIDE 16896          // 8*64*32 num + 512 norm

typedef short bf16x8 __attribute__((ext_vector_type(8)));
typedef float f32x4 __attribute__((ext_vector_type(4)));

#define MFMA(a,b,c) __builtin_amdgcn_mfma_f32_16x16x32_bf16((a),(b),(c),0,0,0)

__device__ __forceinline__ f32x4 zero4() { f32x4 z; z[0]=0.f; z[1]=0.f; z[2]=0.f; z[3]=0.f; return z; }

__device__ __forceinline__ ushort bf_rne(float f) {
  unsigned u = __float_as_uint(f);
  return (ushort)((u + 0x7FFFu + ((u >> 16) & 1u)) >> 16);
}
__device__ __forceinline__ void split2(float f, ushort& h, ushort& l) {
  h = bf_rne(f);
  float fh = __uint_as_float(((unsigned)h) << 16);
  l = bf_rne(f - fh);
}

// ---------------- K0a ----------------
__global__ __launch_bounds__(256) void k_build_wlog(
    const float* __restrict__ Wx, const float* __restrict__ bx,
    const float* __restrict__ Wsl, const float* __restrict__ bsl,
    const float* __restrict__ temp,
    ushort* __restrict__ wlh, ushort* __restrict__ wll, float* __restrict__ blog)
{
  const int q = blockIdx.x, k = threadIdx.x;
  const int h = q >> 6, s = q & 63;
  const float it = 1.0f / temp[h];
  float acc = 0.f;
#pragma unroll
  for (int c = 0; c < DH; ++c)
    acc = fmaf(Wx[k * HID + h * DH + c], Wsl[c * NS + s], acc);
  acc *= it;
  ushort hh, ll; split2(acc, hh, ll);
  wlh[q * HID + k] = hh; wll[q * HID + k] = ll;
  if (k == 0) {
    float b = bsl[s];
    for (int c = 0; c < DH; ++c) b = fmaf(bx[h * DH + c], Wsl[c * NS + s], b);
    blog[q] = b * it;
  }
}

// ---------------- K0b ----------------
__global__ __launch_bounds__(256) void k_build_wfxt(
    const float* __restrict__ Wfx, ushort* __restrict__ wfxth)
{
  const int c = blockIdx.x, k = threadIdx.x;       // out row c, inner k
  wfxth[c * HID + k] = bf_rne(Wfx[k * HID + c]);
}

// ---------------- K0c ----------------
__global__ __launch_bounds__(256) void k_build_wprojt(
    const float* __restrict__ Wproj, ushort* __restrict__ wpth, ushort* __restrict__ wptl)
{
  const int hc = blockIdx.x, j = threadIdx.x;
  ushort hh, ll; split2(Wproj[hc * HID + j], hh, ll);
  wpth[j * HID + hc] = hh; wptl[j * HID + hc] = ll;
}

// ---------------- Pass 1 ----------------
__global__ __launch_bounds__(512, 4) void k_pass1(
    const float* __restrict__ x, const float* __restrict__ mask,
    const ushort* __restrict__ wlogh, const float* __restrict__ blog,
    const ushort* __restrict__ wfxth, const float* __restrict__ bfx,
    float* __restrict__ partials, int Ntok, int ntiles, int ngrid)
{
  __shared__ ushort xh[MT * 264];        // 16.5 KB  (x hi, row stride 264)
  __shared__ ushort wt[NQ * 40];         // 40 KB    (w^T hi: [q][tok], stride 40)
  __shared__ ushort fxt[HID * 40];       // 20 KB    (fx^T:   [hc][tok], stride 40)
  __shared__ float msk[MT];

  const int t = threadIdx.x;
  const int w = t >> 6, lane = t & 63, lr = lane & 15, lg = lane >> 4;

  float blogr[4], bfxr[2];
#pragma unroll
  for (int cf = 0; cf < 4; ++cf) blogr[cf] = blog[w * 64 + cf * 16 + lr];
#pragma unroll
  for (int cf = 0; cf < 2; ++cf) bfxr[cf] = bfx[w * 32 + cf * 16 + lr];

  f32x4 pool[4][2];
#pragma unroll
  for (int sf = 0; sf < 4; ++sf) { pool[sf][0] = zero4(); pool[sf][1] = zero4(); }
  float nacc[4] = {0.f, 0.f, 0.f, 0.f};

  for (int tile = blockIdx.x; tile < ntiles; tile += ngrid) {
    const int n0 = tile * MT;
    __syncthreads();
    // ---- stage x (hi only) ----
    {
      const int tok = t >> 4, sg = (t & 15) * 16;
      float v[16];
      if (n0 + tok < Ntok) {
        const float4* src = (const float4*)(x + (size_t)(n0 + tok) * HID + sg);
#pragma unroll
        for (int i = 0; i < 4; ++i) { float4 f = src[i]; v[i*4]=f.x; v[i*4+1]=f.y; v[i*4+2]=f.z; v[i*4+3]=f.w; }
      } else {
#pragma unroll
        for (int i = 0; i < 16; ++i) v[i] = 0.f;
      }
      union { ushort u[16]; bf16x8 v8[2]; } H;
#pragma unroll
      for (int i = 0; i < 16; ++i) H.u[i] = bf_rne(v[i]);
      *reinterpret_cast<bf16x8*>(&xh[tok * 264 + sg]) = H.v8[0];
      *reinterpret_cast<bf16x8*>(&xh[tok * 264 + sg + 8]) = H.v8[1];
      if (t < MT) msk[t] = (n0 + t < Ntok) ? mask[n0 + t] : 0.f;
    }
    __syncthreads();

    // ---- logits (1 product: precision-insensitive; pooling averages errors out) ----
    f32x4 acc[2][4];
#pragma unroll
    for (int rf = 0; rf < 2; ++rf)
#pragma unroll
      for (int cf = 0; cf < 4; ++cf) acc[rf][cf] = zero4();
#pragma unroll
    for (int kk = 0; kk < HID; kk += 32) {
      bf16x8 ah0 = *reinterpret_cast<const bf16x8*>(&xh[lr * 264 + kk + lg * 8]);
      bf16x8 ah1 = *reinterpret_cast<const bf16x8*>(&xh[(16 + lr) * 264 + kk + lg * 8]);
#pragma unroll
      for (int cf = 0; cf < 4; ++cf) {
        bf16x8 bh = *reinterpret_cast<const bf16x8*>(wlogh + (size_t)(w * 64 + cf * 16 + lr) * HID + kk + lg * 8);
        acc[0][cf] = MFMA(ah0, bh, acc[0][cf]);
        acc[1][cf] = MFMA(ah1, bh, acc[1][cf]);
      }
    }
    // ---- softmax (in place on acc), wave-local via shfl ----
#pragma unroll
    for (int rf = 0; rf < 2; ++rf)
#pragma unroll
      for (int r = 0; r < 4; ++r) {
        float mx = -1e30f;
#pragma unroll
        for (int cf = 0; cf < 4; ++cf) { float vv = acc[rf][cf][r] + blogr[cf]; acc[rf][cf][r] = vv; mx = fmaxf(mx, vv); }
        mx = fmaxf(mx, __shfl_xor(mx, 1)); mx = fmaxf(mx, __shfl_xor(mx, 2));
        mx = fmaxf(mx, __shfl_xor(mx, 4)); mx = fmaxf(mx, __shfl_xor(mx, 8));
        float sm = 0.f;
#pragma unroll
        for (int cf = 0; cf < 4; ++cf) { float e = __expf(acc[rf][cf][r] - mx); acc[rf][cf][r] = e; sm += e; }
        sm += __shfl_xor(sm, 1); sm += __shfl_xor(sm, 2); sm += __shfl_xor(sm, 4); sm += __shfl_xor(sm, 8);
        const float sc = msk[rf * 16 + lg * 4 + r] / sm;
#pragma unroll
        for (int cf = 0; cf < 4; ++cf) acc[rf][cf][r] *= sc;
      }
    // ---- write w^T + norm acc ----
#pragma unroll
    for (int rf = 0; rf < 2; ++rf)
#pragma unroll
      for (int cf = 0; cf < 4; ++cf)
#pragma unroll
        for (int r = 0; r < 4; ++r) {
          const int tok = rf * 16 + lg * 4 + r;
          const int q = w * 64 + cf * 16 + lr;
          wt[q * 40 + tok] = bf_rne(acc[rf][cf][r]);
          nacc[cf] += acc[rf][cf][r];
        }
    // ---- fx GEMM (1 product) ----
    f32x4 fa[2][2];
    fa[0][0] = zero4(); fa[0][1] = zero4(); fa[1][0] = zero4(); fa[1][1] = zero4();
#pragma unroll
    for (int kk = 0; kk < HID; kk += 32) {
      bf16x8 ah0 = *reinterpret_cast<const bf16x8*>(&xh[lr * 264 + kk + lg * 8]);
      bf16x8 ah1 = *reinterpret_cast<const bf16x8*>(&xh[(16 + lr) * 264 + kk + lg * 8]);
#pragma unroll
      for (int cf = 0; cf < 2; ++cf) {
        bf16x8 bh = *reinterpret_cast<const bf16x8*>(wfxth + (size_t)(w * 32 + cf * 16 + lr) * HID + kk + lg * 8);
        fa[0][cf] = MFMA(ah0, bh, fa[0][cf]);
        fa[1][cf] = MFMA(ah1, bh, fa[1][cf]);
      }
    }
#pragma unroll
    for (int rf = 0; rf < 2; ++rf)
#pragma unroll
      for (int cf = 0; cf < 2; ++cf)
#pragma unroll
        for (int r = 0; r < 4; ++r) {
          const int tok = rf * 16 + lg * 4 + r;
          const int hc = w * 32 + cf * 16 + lr;
          fxt[hc * 40 + tok] = bf_rne(fa[rf][cf][r] + bfxr[cf]);
        }
    __syncthreads();
    // ---- pooling MFMA: num[s][hc] += w^T * fx  (head w, K=32 toks, persistent acc) ----
    {
      bf16x8 b0 = *reinterpret_cast<const bf16x8*>(&fxt[(w * 32 + lr) * 40 + lg * 8]);
      bf16x8 b1 = *reinterpret_cast<const bf16x8*>(&fxt[(w * 32 + 16 + lr) * 40 + lg * 8]);
#pragma unroll
      for (int sf = 0; sf < 4; ++sf) {
        bf16x8 a = *reinterpret_cast<const bf16x8*>(&wt[(w * 64 + sf * 16 + lr) * 40 + lg * 8]);
        pool[sf][0] = MFMA(a, b0, pool[sf][0]);
        pool[sf][1] = MFMA(a, b1, pool[sf][1]);
      }
    }
  }
  // ---- epilogue: per-block partials ----
  float* pb = partials + (size_t)blockIdx.x * PSTRIDE;
#pragma unroll
  for (int sf = 0; sf < 4; ++sf)
#pragma unroll
    for (int cp = 0; cp < 2; ++cp)
#pragma unroll
      for (int r = 0; r < 4; ++r) {
        const int s = sf * 16 + lg * 4 + r;
        const int hcl = cp * 16 + lr;
        pb[w * 2048 + s * 32 + hcl] = pool[sf][cp][r];
      }
#pragma unroll
  for (int cf = 0; cf < 4; ++cf) {
    float v = nacc[cf];
    v += __shfl_xor(v, 16); v += __shfl_xor(v, 32);
    if (lg == 0) pb[16384 + w * 64 + cf * 16 + lr] = v;
  }
}

// ---------------- K2 reductions ----------------
__global__ __launch_bounds__(256) void k_reduce_norm(
    const float* __restrict__ partials, float* __restrict__ normbuf, int nb)
{
  const int p = blockIdx.x * 256 + threadIdx.x;
  float s = 0.f;
  for (int b = 0; b < nb; ++b) s += partials[(size_t)b * PSTRIDE + 16384 + p];
  normbuf[p] = s;
}

__global__ __launch_bounds__(256) void k_reduce_num(
    const float* __restrict__ partials, const float* __restrict__ normbuf,
    float* __restrict__ st, int nb)
{
  const int pidx = blockIdx.x * 256 + threadIdx.x;   // q*32 + c
  float acc = 0.f;
  for (int b = 0; b < nb; ++b) acc += partials[(size_t)b * PSTRIDE + pidx];
  st[pidx] = acc / (normbuf[pidx >> 5] + 1e-5f);
}

// ---------------- SDPA ----------------
__global__ __launch_bounds__(64) void k_sdpa(
    const float* __restrict__ st, const float* __restrict__ Wqkv,
    ushort* __restrict__ oslth, ushort* __restrict__ osltl)
{
  __shared__ float stt[NS][DH + 1];
  __shared__ float kt[NS][DH + 1];
  __shared__ float vt[NS][DH + 1];
  const int h = blockIdx.x, sr = threadIdx.x;
  for (int i = sr; i < NS * DH; i += 64) stt[i >> 5][i & 31] = st[(size_t)h * NS * DH + i];
  __syncthreads();
  float qr[DH];
#pragma unroll
  for (int c = 0; c < DH; ++c) {
    float aq = 0.f, ak = 0.f, av = 0.f;
#pragma unroll
    for (int i = 0; i < DH; ++i) {
      const float sv = stt[sr][i];
      aq = fmaf(sv, Wqkv[i * 96 + c], aq);
      ak = fmaf(sv, Wqkv[i * 96 + 32 + c], ak);
      av = fmaf(sv, Wqkv[i * 96 + 64 + c], av);
    }
    qr[c] = aq; kt[sr][c] = ak; vt[sr][c] = av;
  }
  __syncthreads();
  float sc[NS];
  float m = -1e30f;
  const float scale = 0.17677669529663687f;
#pragma unroll
  for (int tt = 0; tt < NS; ++tt) {
    float a = 0.f;
#pragma unroll
    for (int c = 0; c < DH; ++c) a = fmaf(qr[c], kt[tt][c], a);
    a *= scale; sc[tt] = a; m = fmaxf(m, a);
  }
  float sum = 0.f;
#pragma unroll
  for (int tt = 0; tt < NS; ++tt) { const float e = __expf(sc[tt] - m); sc[tt] = e; sum += e; }
  const float inv = 1.f / sum;
#pragma unroll
  for (int c = 0; c < DH; ++c) {
    float o = 0.f;
#pragma unroll
    for (int tt = 0; tt < NS; ++tt) o = fmaf(sc[tt], vt[tt][c], o);
    o *= inv;
    ushort hh, ll; split2(o, hh, ll);
    oslth[(h * DH + c) * NS + sr] = hh;
    osltl[(h * DH + c) * NS + sr] = ll;
  }
}

// ---------------- Pass 3 ----------------
__global__ __launch_bounds__(512, 2) void k_pass3(
    const float* __restrict__ x, const float* __restrict__ mask,
    const ushort* __restrict__ wlogh, const ushort* __restrict__ wlogl,
    const float* __restrict__ blog,
    const ushort* __restrict__ oslth, const ushort* __restrict__ osltl,
    const ushort* __restrict__ wpth, const ushort* __restrict__ wptl,
    const float* __restrict__ bproj,
    float* __restrict__ out, int Ntok, int ntiles, int ngrid)
{
  __shared__ ushort xh[MT * 264];        // also ox_hi after stage1
  __shared__ ushort xl[MT * 264];        // also ox_lo
  __shared__ ushort wh[MT * 520];        // w hi: [tok][q], stride 520
  __shared__ ushort wl[MT * 520];
  __shared__ float msk[MT];

  const int t = threadIdx.x;
  const int w = t >> 6, lane = t & 63, lr = lane & 15, lg = lane >> 4;

  float blogr[4], bprr[2];
#pragma unroll
  for (int cf = 0; cf < 4; ++cf) blogr[cf] = blog[w * 64 + cf * 16 + lr];
#pragma unroll
  for (int cf = 0; cf < 2; ++cf) bprr[cf] = bproj[w * 32 + cf * 16 + lr];

  for (int tile = blockIdx.x; tile < ntiles; tile += ngrid) {
    const int n0 = tile * MT;
    __syncthreads();
    // ---- stage x hi/lo ----
    {
      const int tok = t >> 4, sg = (t & 15) * 16;
      float v[16];
      if (n0 + tok < Ntok) {
        const float4* src = (const float4*)(x + (size_t)(n0 + tok) * HID + sg);
#pragma unroll
        for (int i = 0; i < 4; ++i) { float4 f = src[i]; v[i*4]=f.x; v[i*4+1]=f.y; v[i*4+2]=f.z; v[i*4+3]=f.w; }
      } else {
#pragma unroll
        for (int i = 0; i < 16; ++i) v[i] = 0.f;
      }
      union { ushort u[16]; bf16x8 v8[2]; } H, L;
#pragma unroll
      for (int i = 0; i < 16; ++i) split2(v[i], H.u[i], L.u[i]);
      *reinterpret_cast<bf16x8*>(&xh[tok * 264 + sg]) = H.v8[0];
      *reinterpret_cast<bf16x8*>(&xh[tok * 264 + sg + 8]) = H.v8[1];
      *reinterpret_cast<bf16x8*>(&xl[tok * 264 + sg]) = L.v8[0];
      *reinterpret_cast<bf16x8*>(&xl[tok * 264 + sg + 8]) = L.v8[1];
      if (t < MT) msk[t] = (n0 + t < Ntok) ? mask[n0 + t] : 0.f;
    }
    __syncthreads();

    // ---- logits, 3-product split (precision-critical: feeds scatter) ----
    f32x4 acc[2][4];
#pragma unroll
    for (int rf = 0; rf < 2; ++rf)
#pragma unroll
      for (int cf = 0; cf < 4; ++cf) acc[rf][cf] = zero4();
#pragma unroll
    for (int kk = 0; kk < HID; kk += 32) {
      bf16x8 ah0 = *reinterpret_cast<const bf16x8*>(&xh[lr * 264 + kk + lg * 8]);
      bf16x8 ah1 = *reinterpret_cast<const bf16x8*>(&xh[(16 + lr) * 264 + kk + lg * 8]);
      bf16x8 al0 = *reinterpret_cast<const bf16x8*>(&xl[lr * 264 + kk + lg * 8]);
      bf16x8 al1 = *reinterpret_cast<const bf16x8*>(&xl[(16 + lr) * 264 + kk + lg * 8]);
#pragma unroll
      for (int cf = 0; cf < 4; ++cf) {
        const size_t bo = (size_t)(w * 64 + cf * 16 + lr) * HID + kk + lg * 8;
        bf16x8 bh = *reinterpret_cast<const bf16x8*>(wlogh + bo);
        bf16x8 bl = *reinterpret_cast<const bf16x8*>(wlogl + bo);
        acc[0][cf] = MFMA(ah0, bh, acc[0][cf]);
        acc[0][cf] = MFMA(al0, bh, acc[0][cf]);
        acc[0][cf] = MFMA(ah0, bl, acc[0][cf]);
        acc[1][cf] = MFMA(ah1, bh, acc[1][cf]);
        acc[1][cf] = MFMA(al1, bh, acc[1][cf]);
        acc[1][cf] = MFMA(ah1, bl, acc[1][cf]);
      }
    }
    // ---- softmax in place ----
#pragma unroll
    for (int rf = 0; rf < 2; ++rf)
#pragma unroll
      for (int r = 0; r < 4; ++r) {
        float mx = -1e30f;
#pragma unroll
        for (int cf = 0; cf < 4; ++cf) { float vv = acc[rf][cf][r] + blogr[cf]; acc[rf][cf][r] = vv; mx = fmaxf(mx, vv); }
        mx = fmaxf(mx, __shfl_xor(mx, 1)); mx = fmaxf(mx, __shfl_xor(mx, 2));
        mx = fmaxf(mx, __shfl_xor(mx, 4)); mx = fmaxf(mx, __shfl_xor(mx, 8));
        float sm = 0.f;
#pragma unroll
        for (int cf = 0; cf < 4; ++cf) { float e = __expf(acc[rf][cf][r] - mx); acc[rf][cf][r] = e; sm += e; }
        sm += __shfl_xor(sm, 1); sm += __shfl_xor(sm, 2); sm += __shfl_xor(sm, 4); sm += __shfl_xor(sm, 8);
        const float sc = msk[rf * 16 + lg * 4 + r] / sm;
#pragma unroll
        for (int cf = 0; cf < 4; ++cf) acc[rf][cf][r] *= sc;
      }
    // ---- write w hi/lo [tok][q] ----
#pragma unroll
    for (int rf = 0; rf < 2; ++rf)
#pragma unroll
      for (int cf = 0; cf < 4; ++cf)
#pragma unroll
        for (int r = 0; r < 4; ++r) {
          const int tok = rf * 16 + lg * 4 + r;
          const int q = w * 64 + cf * 16 + lr;
          ushort hh, ll; split2(acc[rf][cf][r], hh, ll);
          wh[tok * 520 + q] = hh; wl[tok * 520 + q] = ll;
        }
    __syncthreads();

    // ---- stage 1: ox[tok][hc] = sum_s w[tok][h*64+s] * osl[h][s][c]  (head w, K=64) ----
    f32x4 s1[2][2];
    s1[0][0] = zero4(); s1[0][1] = zero4(); s1[1][0] = zero4(); s1[1][1] = zero4();
#pragma unroll
    for (int kk = 0; kk < NS; kk += 32) {
#pragma unroll
      for (int rf = 0; rf < 2; ++rf) {
        bf16x8 a_h = *reinterpret_cast<const bf16x8*>(&wh[(rf * 16 + lr) * 520 + w * 64 + kk + lg * 8]);
        bf16x8 a_l = *reinterpret_cast<const bf16x8*>(&wl[(rf * 16 + lr) * 520 + w * 64 + kk + lg * 8]);
#pragma unroll
        for (int cf = 0; cf < 2; ++cf) {
          const size_t bo = (size_t)(w * 32 + cf * 16 + lr) * NS + kk + lg * 8;
          bf16x8 bh = *reinterpret_cast<const bf16x8*>(oslth + bo);
          bf16x8 bl = *reinterpret_cast<const bf16x8*>(osltl + bo);
          s1[rf][cf] = MFMA(a_h, bh, s1[rf][cf]);
          s1[rf][cf] = MFMA(a_l, bh, s1[rf][cf]);
          s1[rf][cf] = MFMA(a_h, bl, s1[rf][cf]);
        }
      }
    }
    // write ox hi/lo into xh/xl space
#pragma unroll
    for (int rf = 0; rf < 2; ++rf)
#pragma unroll
      for (int cf = 0; cf < 2; ++cf)
#pragma unroll
        for (int r = 0; r < 4; ++r) {
          const int tok = rf * 16 + lg * 4 + r;
          const int hc = w * 32 + cf * 16 + lr;
          ushort hh, ll; split2(s1[rf][cf][r], hh, ll);
          xh[tok * 264 + hc] = hh; xl[tok * 264 + hc] = ll;
        }
    __syncthreads();

    // ---- stage 2: out[tok][j] = mask*(mask*(ox @ Wproj) + bproj)  (K=256, j-slice w*32) ----
    f32x4 s2[2][2];
    s2[0][0] = zero4(); s2[0][1] = zero4(); s2[1][0] = zero4(); s2[1][1] = zero4();
#pragma unroll
    for (int kk = 0; kk < HID; kk += 32) {
#pragma unroll
      for (int rf = 0; rf < 2; ++rf) {
        bf16x8 a_h = *reinterpret_cast<const bf16x8*>(&xh[(rf * 16 + lr) * 264 + kk + lg * 8]);
        bf16x8 a_l = *reinterpret_cast<const bf16x8*>(&xl[(rf * 16 + lr) * 264 + kk + lg * 8]);
#pragma unroll
        for (int cf = 0; cf < 2; ++cf) {
          const size_t bo = (size_t)(w * 32 + cf * 16 + lr) * HID + kk + lg * 8;
          bf16x8 bh = *reinterpret_cast<const bf16x8*>(wpth + bo);
          bf16x8 bl = *reinterpret_cast<const bf16x8*>(wptl + bo);
          s2[rf][cf] = MFMA(a_h, bh, s2[rf][cf]);
          s2[rf][cf] = MFMA(a_l, bh, s2[rf][cf]);
          s2[rf][cf] = MFMA(a_h, bl, s2[rf][cf]);
        }
      }
    }
#pragma unroll
    for (int rf = 0; rf < 2; ++rf)
#pragma unroll
      for (int cf = 0; cf < 2; ++cf)
#pragma unroll
        for (int r = 0; r < 4; ++r) {
          const int tok = rf * 16 + lg * 4 + r;
          const int n = n0 + tok;
          if (n < Ntok) {
            const int j = w * 32 + cf * 16 + lr;
            const float mk = msk[tok];
            out[(size_t)n * HID + j] = mk * (mk * s2[rf][cf][r] + bprr[cf]);
          }
        }
  }
}

extern "C" void kernel_launch(void* const* d_in, const int* in_sizes, int n_in,
                              void* d_out, int out_size, void* d_ws, size_t ws_size,
                              hipStream_t stream)
{
  const float* x     = (const float*)d_in[0];
  const float* mask  = (const float*)d_in[1];
  const float* Wfx   = (const float*)d_in[2];
  const float* bfx   = (const float*)d_in[3];
  const float* Wx    = (const float*)d_in[4];
  const float* bx    = (const float*)d_in[5];
  const float* Wsl   = (const float*)d_in[6];
  const float* bsl   = (const float*)d_in[7];
  const float* Wqkv  = (const float*)d_in[8];
  const float* Wproj = (const float*)d_in[9];
  const float* bproj = (const float*)d_in[10];
  const float* temp  = (const float*)d_in[11];
  float* out = (float*)d_out;

  const int Ntok = in_sizes[0] / HID;             // 200000
  const int ntiles = (Ntok + MT - 1) / MT;        // 6250

  char* ws = (char*)d_ws;
  size_t off = 0;
  ushort* wlogh = (ushort*)(ws + off); off += (size_t)NQ * HID * 2;    // 256 KB
  ushort* wlogl = (ushort*)(ws + off); off += (size_t)NQ * HID * 2;
  float*  blog  = (float*)(ws + off);  off += NQ * 4;
  ushort* wfxth = (ushort*)(ws + off); off += (size_t)HID * HID * 2;   // 128 KB
  ushort* wpth  = (ushort*)(ws + off); off += (size_t)HID * HID * 2;
  ushort* wptl  = (ushort*)(ws + off); off += (size_t)HID * HID * 2;
  ushort* oslth = (ushort*)(ws + off); off += (size_t)NQ * DH * 2;     // 32 KB
  ushort* osltl = (ushort*)(ws + off); off += (size_t)NQ * DH * 2;
  float*  stb   = (float*)(ws + off);  off += (size_t)NQ * DH * 4;     // 64 KB
  float*  normb = (float*)(ws + off);  off += NQ * 4;
  int nb1 = 512;
  while (nb1 > 1 && off + (size_t)nb1 * PSTRIDE * 4 > ws_size) nb1 >>= 1;
  float* partials = (float*)(ws + off);

  k_build_wlog<<<dim3(NQ), dim3(256), 0, stream>>>(Wx, bx, Wsl, bsl, temp, wlogh, wlogl, blog);
  k_build_wfxt<<<dim3(HID), dim3(256), 0, stream>>>(Wfx, wfxth);
  k_build_wprojt<<<dim3(HID), dim3(256), 0, stream>>>(Wproj, wpth, wptl);
  k_pass1<<<dim3(nb1), dim3(512), 0, stream>>>(x, mask, wlogh, blog, wfxth, bfx,
                                               partials, Ntok, ntiles, nb1);
  k_reduce_norm<<<dim3(2), dim3(256), 0, stream>>>(partials, normb, nb1);
  k_reduce_num<<<dim3(64), dim3(256), 0, stream>>>(partials, normb, stb, nb1);
  k_sdpa<<<dim3(NH), dim3(64), 0, stream>>>(stb, Wqkv, oslth, osltl);
  k_pass3<<<dim3(256), dim3(512), 0, stream>>>(x, mask, wlogh, wlogl, blog,
                                               oslth, osltl, wpth, wptl, bproj,
                                               out, Ntok, ntiles, 256);
}